// Round 8
// baseline (243.914 us; speedup 1.0000x reference)
//
#include <hip/hip_runtime.h>
#include <hip/hip_bf16.h>

typedef __attribute__((ext_vector_type(4))) float f32x4;
typedef __attribute__((ext_vector_type(8))) short bf16x8;

#define MFMA16(a, b, c) __builtin_amdgcn_mfma_f32_16x16x32_bf16(a, b, c, 0, 0, 0)

constexpr int BATCH = 4;
constexpr int SEQ   = 2048;
constexpr int DIM   = 1024;

__device__ __forceinline__ ushort f2b(float f) {
  __hip_bfloat16 h = __float2bfloat16(f);
  union { __hip_bfloat16 h; ushort u; } cv; cv.h = h; return cv.u;
}

// ---------------- fused fp32 -> bf16 convert ----------------
__global__ __launch_bounds__(256) void cvt_all(
    const float* __restrict__ x, const float* __restrict__ wq,
    const float* __restrict__ wk, const float* __restrict__ wv,
    ushort* __restrict__ xb, ushort* __restrict__ wb) {
  int i = blockIdx.x * 256 + threadIdx.x;
  const float* src; ushort* dst; int off;
  if (i < 2097152) { src = x; dst = xb; off = i; }
  else {
    int j = i - 2097152;
    int s = j >> 18;
    off = j & 262143;
    src = (s == 0) ? wq : (s == 1) ? wk : wv;
    dst = wb + s * 1048576;
  }
  float4 v = reinterpret_cast<const float4*>(src)[off];
  ushort4 o;
  o.x = f2b(v.x); o.y = f2b(v.y); o.z = f2b(v.z); o.w = f2b(v.w);
  reinterpret_cast<ushort4*>(dst)[off] = o;
}

__device__ __forceinline__ void gload_lds16(const void* g, void* l) {
  __builtin_amdgcn_global_load_lds(
      (const __attribute__((address_space(1))) unsigned int*)g,
      (__attribute__((address_space(3))) unsigned int*)l, 16, 0, 0);
}

#define VWAIT(n) asm volatile("s_waitcnt vmcnt(" #n ")" ::: "memory")
#define BAR() __builtin_amdgcn_s_barrier()

// ====== 256xBN 8-wave GEMM: A staged in LDS, B direct global->reg ======
// C = scale*(A.B^T) variants. A:[M][Kd] bf16 K-contig, B:[N'][Kd] bf16.
// 8 waves 2Mx4N: wave = 128 rows x (BN/4) cols. Per K-tile(64):
//   BAR1; stage A(t+1) (4 gload_lds); VWAIT(4+2NF) [drains A(t), leaves
//   {b(t) regs in flight OK + batch t+1}]; 4 groups {4 ds_read A, 4NF MFMA};
//   BAR2; load B(t+1) frags to regs (compiler-tracked waits).
// LDS = A dbuf only = 64 KiB. B-frag global pattern: 16 lanes x 64B lines.
// MODE 0 qk: route by seg=n0>>10 to C0/C1 + bias.  MODE 1 s: exp + lpart.
// MODE 2 v: transposed write to vt via LDS bounce + bias.  MODE 3 pv: /rowsum.
template <int BN_, int MODE>
__device__ __forceinline__ void gemm_body(
    const ushort* __restrict__ Ag, const ushort* __restrict__ Bg,
    void* __restrict__ C0, void* __restrict__ C1,
    const float* __restrict__ x0, const float* __restrict__ x1,
    float* __restrict__ lpart,
    int N, int Kd, float scale, long sA, long sB, long sC)
{
  constexpr int NF = BN_ / 64;            // col-frags per wave (4 or 2)
  constexpr int ASZ = 256 * 64;
  __shared__ ushort SH[2 * ASZ];          // 64 KiB (A dbuf; epilogue reuse)

  int nwg = gridDim.x * gridDim.y;
  int id = blockIdx.y * gridDim.x + blockIdx.x;
  int swz = (nwg & 7) ? id : ((id & 7) * (nwg >> 3) + (id >> 3));
  const int m0 = (swz / gridDim.x) * 256;
  const int n0 = (swz % gridDim.x) * BN_;
  const int bz = blockIdx.z;
  const char* Ab = (const char*)(Ag + (size_t)bz * sA);
  const char* Bb = (const char*)(Bg + (size_t)bz * sB);
  const int t = threadIdx.x;
  const int lane = t & 63;
  const int w = t >> 6;
  const int wm = w >> 2, wn = w & 3;
  const size_t pA = (size_t)Kd * 2;
  const size_t pB = (size_t)Kd * 2;
  const int nt = Kd >> 6;

  auto stageH = [&](ushort* ldsb, const char* gb) {
#pragma unroll
    for (int j = 0; j < 2; ++j) {
      int g = j * 512 + t;
      int r = g >> 3;
      int cb = ((g & 7) << 4) ^ ((r & 7) << 4);
      gload_lds16(gb + (size_t)r * pA + cb,
                  (char*)ldsb + (size_t)((j * 512 + (t & ~63)) << 4));
    }
  };
  auto ldfrag = [&](const ushort* base, int row, int ks) -> bf16x8 {
    int L = row * 128 + ks * 64 + ((lane >> 4) << 4);
    return *(const bf16x8*)((const char*)base + (L ^ ((row & 7) << 4)));
  };

  f32x4 acc[8][NF];
#pragma unroll
  for (int i = 0; i < 8; ++i)
#pragma unroll
    for (int j = 0; j < NF; ++j) acc[i][j] = 0.f;

  bf16x8 a[2][2];
  bf16x8 b[NF][2];

  auto ldB = [&](int tt) {
#pragma unroll
    for (int nf = 0; nf < NF; ++nf) {
      const char* p = Bb + (size_t)(n0 + wn * (16 * NF) + nf * 16 + (lane & 15)) * pB
                      + (size_t)tt * 128 + ((lane >> 4) << 4);
      b[nf][0] = *(const bf16x8*)(p);
      b[nf][1] = *(const bf16x8*)(p + 64);
    }
  };

  // ---- prologue: A(0) staged first, then B(0) regs (order pinned) ----
  stageH(SH, Ab + (size_t)m0 * pA);
  stageH(SH + 128 * 64, Ab + (size_t)(m0 + 128) * pA);
  __builtin_amdgcn_sched_barrier(0);
  ldB(0);

  for (int tt = 0; tt < nt; ++tt) {
    const int buf = tt & 1;
    const ushort* Ac = SH + buf * ASZ;
    ushort* An = SH + (buf ^ 1) * ASZ;
    BAR();                                 // all waves done reading buf^1
    if (tt + 1 < nt) {
      const size_t ko1 = (size_t)(tt + 1) * 128;
      stageH(An, Ab + (size_t)m0 * pA + ko1);
      stageH(An + 128 * 64, Ab + (size_t)(m0 + 128) * pA + ko1);
      if constexpr (NF == 4) VWAIT(12); else VWAIT(8);
    } else {
      VWAIT(0);
    }
#pragma unroll
    for (int gp = 0; gp < 4; ++gp) {
#pragma unroll
      for (int i = 0; i < 2; ++i) {
        int r = wm * 128 + (gp * 2 + i) * 16 + (lane & 15);
        a[i][0] = ldfrag(Ac, r, 0);
        a[i][1] = ldfrag(Ac, r, 1);
      }
      __builtin_amdgcn_s_setprio(1);
#pragma unroll
      for (int i = 0; i < 2; ++i)
#pragma unroll
        for (int nf = 0; nf < NF; ++nf) {
          acc[gp * 2 + i][nf] = MFMA16(a[i][0], b[nf][0], acc[gp * 2 + i][nf]);
          acc[gp * 2 + i][nf] = MFMA16(a[i][1], b[nf][1], acc[gp * 2 + i][nf]);
        }
      __builtin_amdgcn_s_setprio(0);
    }
    BAR();                                 // reads(t) done before stage(t+2)
    if (tt + 1 < nt) ldB(tt + 1);
  }

  // ================= epilogues =================
  if constexpr (MODE == 0) {
    // QK: bias + bf16, routed by segment (N' = 2048 -> Q | K)
    const int seg = n0 >> 10;
    const int n0l = n0 & 1023;
    const float* biasp = seg == 0 ? x0 : x1;
    ushort* Ch = (ushort*)(seg == 0 ? C0 : C1);
#pragma unroll
    for (int mf = 0; mf < 8; ++mf)
#pragma unroll
      for (int nf = 0; nf < NF; ++nf) {
        int gn = n0l + wn * (16 * NF) + nf * 16 + (lane & 15);
        float bb = biasp[gn];
#pragma unroll
        for (int r = 0; r < 4; ++r) {
          int gm = m0 + wm * 128 + mf * 16 + (lane >> 4) * 4 + r;
          Ch[(size_t)gm * N + gn] = f2b(acc[mf][nf][r] * scale + bb);
        }
      }
  } else if constexpr (MODE == 1) {
    // S: P = exp(scale*acc) bf16 + per-row partial sums -> lpart[b][row][8]
    ushort* Ch = (ushort*)C0 + (size_t)bz * sC;
    float rs[8][4];
#pragma unroll
    for (int mf = 0; mf < 8; ++mf)
#pragma unroll
      for (int r = 0; r < 4; ++r) rs[mf][r] = 0.f;
#pragma unroll
    for (int mf = 0; mf < 8; ++mf)
#pragma unroll
      for (int nf = 0; nf < NF; ++nf) {
        int gn = n0 + wn * (16 * NF) + nf * 16 + (lane & 15);
#pragma unroll
        for (int r = 0; r < 4; ++r) {
          int gm = m0 + wm * 128 + mf * 16 + (lane >> 4) * 4 + r;
          float v = __expf(acc[mf][nf][r] * scale);
          Ch[(size_t)gm * N + gn] = f2b(v);
          rs[mf][r] += v;
        }
      }
#pragma unroll
    for (int mf = 0; mf < 8; ++mf)
#pragma unroll
      for (int r = 0; r < 4; ++r) {
#pragma unroll
        for (int off = 1; off < 16; off <<= 1)
          rs[mf][r] += __shfl_xor(rs[mf][r], off);
      }
    __syncthreads();
    float* Lred = (float*)SH;              // [4 wn][256 rows]
    f32x4 wv = 0.f;
#pragma unroll
    for (int mf = 0; mf < 8; ++mf)
      if ((lane & 15) == mf) {
        wv[0] = rs[mf][0]; wv[1] = rs[mf][1]; wv[2] = rs[mf][2]; wv[3] = rs[mf][3];
      }
    if ((lane & 15) < 8)
      *(f32x4*)&Lred[wn * 256 + wm * 128 + (lane & 15) * 16 + (lane >> 4) * 4] = wv;
    __syncthreads();
    if (t < 256) {
      float s = Lred[t] + Lred[256 + t] + Lred[512 + t] + Lred[768 + t];
      lpart[((size_t)bz * SEQ + m0 + t) * 8 + (n0 >> 8)] = s;
    }
  } else if constexpr (MODE == 2) {
    // V: write transposed to vt[b][d][token] via LDS bounce (2 token-halves)
    const int b_ = m0 >> 11;
    const int tok0 = m0 & 2047;
    ushort* vtb = (ushort*)C0 + (size_t)b_ * DIM * SEQ;
    ushort* T = SH;                        // [128 d][136]
    __syncthreads();
#pragma unroll
    for (int h = 0; h < 2; ++h) {
      if (wm == h) {
#pragma unroll
        for (int nf = 0; nf < NF; ++nf) {
          int d_loc = wn * (16 * NF) + nf * 16 + (lane & 15);
          float bvv = x0[n0 + d_loc];
#pragma unroll
          for (int mf = 0; mf < 8; ++mf) {
            ushort4 pk;
            pk.x = f2b(acc[mf][nf][0] + bvv);
            pk.y = f2b(acc[mf][nf][1] + bvv);
            pk.z = f2b(acc[mf][nf][2] + bvv);
            pk.w = f2b(acc[mf][nf][3] + bvv);
            *(ushort4*)&T[d_loc * 136 + mf * 16 + (lane >> 4) * 4] = pk;
          }
        }
      }
      __syncthreads();
      {
        int rr = t >> 2, ch = t & 3;
        ushort* dst = vtb + (size_t)(n0 + rr) * SEQ + tok0 + h * 128 + ch * 32;
#pragma unroll
        for (int i = 0; i < 4; ++i)
          *(bf16x8*)(dst + i * 8) = *(const bf16x8*)&T[rr * 136 + ch * 32 + i * 8];
      }
      __syncthreads();
    }
  } else {
    // PV: O = acc / rowsum(lpart), f32 out
    const float* lp = x0 + (size_t)bz * SEQ * 8;
    float* Cf = (float*)C0 + (size_t)bz * sC;
#pragma unroll
    for (int mf = 0; mf < 8; ++mf) {
      int row0 = m0 + wm * 128 + mf * 16 + (lane >> 4) * 4;
      float inv[4];
#pragma unroll
      for (int r = 0; r < 4; ++r) {
        const f32x4* q = (const f32x4*)(lp + (size_t)(row0 + r) * 8);
        f32x4 u = q[0] + q[1];
        inv[r] = 1.f / (u[0] + u[1] + u[2] + u[3]);
      }
#pragma unroll
      for (int nf = 0; nf < NF; ++nf) {
        int gn = n0 + wn * (16 * NF) + nf * 16 + (lane & 15);
#pragma unroll
        for (int r = 0; r < 4; ++r)
          Cf[(size_t)(row0 + r) * N + gn] = acc[mf][nf][r] * inv[r];
      }
    }
  }
}

__global__ __launch_bounds__(512) void gemm_qk(
    const ushort* __restrict__ Ag, const ushort* __restrict__ Bg,
    void* __restrict__ C0, void* __restrict__ C1,
    const float* __restrict__ b0, const float* __restrict__ b1) {
  gemm_body<256, 0>(Ag, Bg, C0, C1, b0, b1, nullptr, DIM, DIM, 1.0f, 0, 0, 0);
}
__global__ __launch_bounds__(512) void gemm_s(
    const ushort* __restrict__ Ag, const ushort* __restrict__ Bg,
    void* __restrict__ C0, float* __restrict__ lpart) {
  gemm_body<256, 1>(Ag, Bg, C0, nullptr, nullptr, nullptr, lpart,
                    SEQ, DIM, 0.03125f, (long)SEQ * DIM, (long)SEQ * DIM,
                    (long)SEQ * SEQ);
}
__global__ __launch_bounds__(512) void gemm_v(
    const ushort* __restrict__ Ag, const ushort* __restrict__ Bg,
    void* __restrict__ C0, const float* __restrict__ bv) {
  gemm_body<128, 2>(Ag, Bg, C0, nullptr, bv, nullptr, nullptr,
                    DIM, DIM, 1.0f, 0, 0, 0);
}
__global__ __launch_bounds__(512) void gemm_pv(
    const ushort* __restrict__ Ag, const ushort* __restrict__ Bg,
    void* __restrict__ C0, const float* __restrict__ lpart) {
  gemm_body<128, 3>(Ag, Bg, C0, nullptr, lpart, nullptr, nullptr,
                    DIM, SEQ, 1.0f, (long)SEQ * SEQ, (long)DIM * SEQ,
                    (long)SEQ * DIM);
}

// ---------------- launcher ----------------
extern "C" void kernel_launch(void* const* d_in, const int* in_sizes, int n_in,
                              void* d_out, int out_size, void* d_ws, size_t ws_size,
                              hipStream_t stream) {
  const float* x  = (const float*)d_in[0];
  const float* Wq = (const float*)d_in[1];
  const float* bq = (const float*)d_in[2];
  const float* Wk = (const float*)d_in[3];
  const float* bk = (const float*)d_in[4];
  const float* Wv = (const float*)d_in[5];
  const float* bv = (const float*)d_in[6];
  float* out = (float*)d_out;

  char* ws = (char*)d_ws;
  // ws layout (bytes), total 90.2 MB:
  //   [0, 32M)      SP  [4][2048][2048] bf16 (xb at [16M,32M) dead by then)
  //   [32M, 38.3M)  wb  (dead after gemm_v) / lpart overlay
  //   [38.3M, ...)  qb | kb | vt  (16M each)
  ushort* xb = (ushort*)(ws + 16777216);
  ushort* wb = (ushort*)(ws + 33554432);
  ushort* qb = (ushort*)(ws + 39845888);
  ushort* kb = (ushort*)(ws + 56623104);
  ushort* vt = (ushort*)(ws + 73400320);
  ushort* SP = (ushort*)(ws);
  float* lpart = (float*)(ws + 33554432);  // [4][2048][8] f32, overlays dead wb

  cvt_all<<<11264, 256, 0, stream>>>(x, Wq, Wk, Wv, xb, wb);
  // Q,K: [8192 x 2048] = X . [Wq;Wk]^T + bias.  256 blocks.
  gemm_qk<<<dim3(8, 32, 1), 512, 0, stream>>>(xb, wb, qb, kb, bq, bk);
  // V: [8192 x 1024] = X . Wv^T + bias, transposed to vt.  256 blocks.
  gemm_v<<<dim3(8, 32, 1), 512, 0, stream>>>(xb, wb + 2097152, vt, bv);
  // P = exp(Q K^T / 32) -> SP (+ row partial sums -> lpart).  256 blocks.
  gemm_s<<<dim3(8, 8, 4), 512, 0, stream>>>(qb, kb, SP, lpart);
  // O = (P V) / rowsum.  256 blocks.
  gemm_pv<<<dim3(8, 8, 4), 512, 0, stream>>>(SP, vt, out, lpart);
}

// Round 10
// 160.997 us; speedup vs baseline: 1.5150x; 1.5150x over previous
//
#include <hip/hip_runtime.h>
#include <hip/hip_bf16.h>

typedef __attribute__((ext_vector_type(4))) float f32x4;
typedef __attribute__((ext_vector_type(8))) short bf16x8;

#define MFMA16(a, b, c) __builtin_amdgcn_mfma_f32_16x16x32_bf16(a, b, c, 0, 0, 0)

constexpr int BATCH = 4;
constexpr int SEQ   = 2048;
constexpr int DIM   = 1024;

__device__ __forceinline__ ushort f2b(float f) {
  __hip_bfloat16 h = __float2bfloat16(f);
  union { __hip_bfloat16 h; ushort u; } cv; cv.h = h; return cv.u;
}

// ---------------- fused fp32 -> bf16 convert ----------------
__global__ __launch_bounds__(256) void cvt_all(
    const float* __restrict__ x, const float* __restrict__ wq,
    const float* __restrict__ wk, const float* __restrict__ wv,
    ushort* __restrict__ xb, ushort* __restrict__ wb) {
  int i = blockIdx.x * 256 + threadIdx.x;
  const float* src; ushort* dst; int off;
  if (i < 2097152) { src = x; dst = xb; off = i; }
  else {
    int j = i - 2097152;
    int s = j >> 18;
    off = j & 262143;
    src = (s == 0) ? wq : (s == 1) ? wk : wv;
    dst = wb + s * 1048576;
  }
  float4 v = reinterpret_cast<const float4*>(src)[off];
  ushort4 o;
  o.x = f2b(v.x); o.y = f2b(v.y); o.z = f2b(v.z); o.w = f2b(v.w);
  reinterpret_cast<ushort4*>(dst)[off] = o;
}

__device__ __forceinline__ void gload_lds16(const void* g, void* l) {
  __builtin_amdgcn_global_load_lds(
      (const __attribute__((address_space(1))) unsigned int*)g,
      (__attribute__((address_space(3))) unsigned int*)l, 16, 0, 0);
}

#define VWAIT(n) asm volatile("s_waitcnt vmcnt(" #n ")" ::: "memory")
#define BAR() __builtin_amdgcn_s_barrier()

// ============ 256x256 8-wave 2-region GEMM, 1Mx8N wave mapping ============
// (round-6 proven body, unchanged)
// MODE 0 (QK): C routed by seg = n0>>10 to C0/C1 with bias b0/b1, bf16 out.
// MODE 1 (S):  C = exp(scale*acc) bf16 + per-row partial sums -> lpart[b][row][8].
template <int MODE>
__device__ __forceinline__ void gemm256_body(
    const ushort* __restrict__ Ag, const ushort* __restrict__ Bg,
    void* __restrict__ C0, void* __restrict__ C1,
    const float* __restrict__ b0, const float* __restrict__ b1,
    float* __restrict__ lpart,
    int N, int Kd, float scale, long sA, long sB, long sC)
{
  constexpr int ASZ = 256 * 64;
  constexpr int BSZ = 256 * 64;
  __shared__ ushort SH[2 * ASZ + 2 * BSZ];

  int nwg = gridDim.x * gridDim.y;
  int id = blockIdx.y * gridDim.x + blockIdx.x;
  int swz = (nwg & 7) ? id : ((id & 7) * (nwg >> 3) + (id >> 3));
  const int m0 = (swz / gridDim.x) * 256;
  const int n0 = (swz % gridDim.x) * 256;
  const int bz = blockIdx.z;
  const char* Ab = (const char*)(Ag + (size_t)bz * sA);
  const char* Bb = (const char*)(Bg + (size_t)bz * sB);
  const int t = threadIdx.x;
  const int lane = t & 63;
  const int w = t >> 6;
  const size_t pA = (size_t)Kd * 2;
  const size_t pB = (size_t)Kd * 2;
  const int nt = Kd >> 6;

  auto stageH = [&](ushort* ldsb, const char* gb, size_t pitch) {
#pragma unroll
    for (int j = 0; j < 2; ++j) {
      int g = j * 512 + t;
      int r = g >> 3;
      int cb = ((g & 7) << 4) ^ ((r & 7) << 4);
      gload_lds16(gb + (size_t)r * pitch + cb,
                  (char*)ldsb + (size_t)((j * 512 + (t & ~63)) << 4));
    }
  };
  auto ldfrag = [&](const ushort* base, int row, int ks) -> bf16x8 {
    int L = row * 128 + ks * 64 + ((lane >> 4) << 4);
    return *(const bf16x8*)((const char*)base + (L ^ ((row & 7) << 4)));
  };

  f32x4 acc[16][2];
#pragma unroll
  for (int i = 0; i < 16; ++i) { acc[i][0] = 0.f; acc[i][1] = 0.f; }

  bf16x8 a[4][2];
  bf16x8 b[2][2];

  // ---- prologue ----
  stageH(SH + 2 * ASZ, Bb + (size_t)n0 * pB, pB);
  stageH(SH + 2 * ASZ + 128 * 64, Bb + (size_t)(n0 + 128) * pB, pB);
  stageH(SH, Ab + (size_t)m0 * pA, pA);
  stageH(SH + 128 * 64, Ab + (size_t)(m0 + 128) * pA, pA);
  VWAIT(0);
  BAR();

  for (int tt = 0; tt < nt; ++tt) {
    const int buf = tt & 1;
    const ushort* Ac = SH + buf * ASZ;
    const ushort* Bc = SH + 2 * ASZ + buf * BSZ;
    ushort* An = SH + (buf ^ 1) * ASZ;
    ushort* Bn = SH + 2 * ASZ + (buf ^ 1) * BSZ;
    const size_t ko1 = (size_t)(tt + 1) * 128;

    // ======== region A: needs B(t) + A-half0(t) ========
    if (tt + 1 < nt) {
      stageH(Bn, Bb + (size_t)n0 * pB + ko1, pB);
      stageH(Bn + 128 * 64, Bb + (size_t)(n0 + 128) * pB + ko1, pB);
      stageH(An, Ab + (size_t)m0 * pA + ko1, pA);
      VWAIT(8);
    } else {
      VWAIT(2);
    }
    BAR();
#pragma unroll
    for (int nf = 0; nf < 2; ++nf) {
      int r = w * 32 + nf * 16 + (lane & 15);
      b[nf][0] = ldfrag(Bc, r, 0);
      b[nf][1] = ldfrag(Bc, r, 1);
    }
#pragma unroll
    for (int g = 0; g < 2; ++g) {
#pragma unroll
      for (int mi = 0; mi < 4; ++mi) {
        int r = (g * 4 + mi) * 16 + (lane & 15);
        a[mi][0] = ldfrag(Ac, r, 0);
        a[mi][1] = ldfrag(Ac, r, 1);
      }
      __builtin_amdgcn_s_setprio(1);
#pragma unroll
      for (int mi = 0; mi < 4; ++mi)
#pragma unroll
        for (int nf = 0; nf < 2; ++nf) {
          acc[g * 4 + mi][nf] = MFMA16(a[mi][0], b[nf][0], acc[g * 4 + mi][nf]);
          acc[g * 4 + mi][nf] = MFMA16(a[mi][1], b[nf][1], acc[g * 4 + mi][nf]);
        }
      __builtin_amdgcn_s_setprio(0);
    }

    // ======== region B: needs A-half1(t) ========
    if (tt + 1 < nt) {
      stageH(An + 128 * 64, Ab + (size_t)(m0 + 128) * pA + ko1, pA);
      VWAIT(8);
    } else {
      VWAIT(0);
    }
    BAR();
#pragma unroll
    for (int g = 2; g < 4; ++g) {
#pragma unroll
      for (int mi = 0; mi < 4; ++mi) {
        int r = (g * 4 + mi) * 16 + (lane & 15);
        a[mi][0] = ldfrag(Ac, r, 0);
        a[mi][1] = ldfrag(Ac, r, 1);
      }
      __builtin_amdgcn_s_setprio(1);
#pragma unroll
      for (int mi = 0; mi < 4; ++mi)
#pragma unroll
        for (int nf = 0; nf < 2; ++nf) {
          acc[g * 4 + mi][nf] = MFMA16(a[mi][0], b[nf][0], acc[g * 4 + mi][nf]);
          acc[g * 4 + mi][nf] = MFMA16(a[mi][1], b[nf][1], acc[g * 4 + mi][nf]);
        }
      __builtin_amdgcn_s_setprio(0);
    }
  }

  if (MODE == 0) {
    const int seg = n0 >> 10;
    const int n0l = n0 & 1023;
    const float* biasp = seg == 0 ? b0 : b1;
    ushort* Ch = (ushort*)(seg == 0 ? C0 : C1);
#pragma unroll
    for (int mf = 0; mf < 16; ++mf)
#pragma unroll
      for (int nf = 0; nf < 2; ++nf) {
        int gn = n0l + w * 32 + nf * 16 + (lane & 15);
        float bb = biasp[gn];
#pragma unroll
        for (int r = 0; r < 4; ++r) {
          int gm = m0 + mf * 16 + (lane >> 4) * 4 + r;
          Ch[(size_t)gm * N + gn] = f2b(acc[mf][nf][r] * scale + bb);
        }
      }
  } else {
    ushort* Ch = (ushort*)C0 + (size_t)bz * sC;
    float rs[16][4];
#pragma unroll
    for (int mf = 0; mf < 16; ++mf)
#pragma unroll
      for (int r = 0; r < 4; ++r) rs[mf][r] = 0.f;
#pragma unroll
    for (int mf = 0; mf < 16; ++mf)
#pragma unroll
      for (int nf = 0; nf < 2; ++nf) {
        int gn = n0 + w * 32 + nf * 16 + (lane & 15);
#pragma unroll
        for (int r = 0; r < 4; ++r) {
          int gm = m0 + mf * 16 + (lane >> 4) * 4 + r;
          float v = __expf(acc[mf][nf][r] * scale);
          Ch[(size_t)gm * N + gn] = f2b(v);
          rs[mf][r] += v;
        }
      }
#pragma unroll
    for (int mf = 0; mf < 16; ++mf)
#pragma unroll
      for (int r = 0; r < 4; ++r) {
#pragma unroll
        for (int off = 1; off < 16; off <<= 1)
          rs[mf][r] += __shfl_xor(rs[mf][r], off);
      }
    __syncthreads();
    float* Lred = (float*)SH;
    f32x4 wv = 0.f;
#pragma unroll
    for (int mf = 0; mf < 16; ++mf)
      if ((lane & 15) == mf) {
        wv[0] = rs[mf][0]; wv[1] = rs[mf][1]; wv[2] = rs[mf][2]; wv[3] = rs[mf][3];
      }
    *(f32x4*)&Lred[w * 256 + (lane & 15) * 16 + (lane >> 4) * 4] = wv;
    __syncthreads();
    if (t < 256) {
      float s = 0.f;
#pragma unroll
      for (int ww = 0; ww < 8; ++ww) s += Lred[ww * 256 + t];
      lpart[((size_t)bz * SEQ + m0 + t) * 8 + (n0 >> 8)] = s;
    }
  }
}

__global__ __launch_bounds__(512) void gemm_qk(
    const ushort* __restrict__ Ag, const ushort* __restrict__ Bg,
    void* __restrict__ C0, void* __restrict__ C1,
    const float* __restrict__ b0, const float* __restrict__ b1) {
  gemm256_body<0>(Ag, Bg, C0, C1, b0, b1, nullptr, DIM, DIM, 1.0f, 0, 0, 0);
}
__global__ __launch_bounds__(512) void gemm_s(
    const ushort* __restrict__ Ag, const ushort* __restrict__ Bg,
    void* __restrict__ C0, float* __restrict__ lpart) {
  gemm256_body<1>(Ag, Bg, C0, nullptr, nullptr, nullptr, lpart,
                  SEQ, DIM, 0.03125f, (long)SEQ * DIM, (long)SEQ * DIM,
                  (long)SEQ * SEQ);
}

// ====== 128x256 8-wave TRIPLE-BUFFERED GEMM (2Mx4N, wave 64x64) ======
// Per K-tile(64):
//   BAR1  [WAR: all waves done reading buf (tt+2)%3 in iter tt-1]
//   stage tile tt+2 (A + 2 B-halves = 6 gload_lds) -> buf (tt+2)%3
//   VWAIT(12)  [own tile-tt loads drained; t+1,t+2 (12) stay in flight]
//   BAR2  [RAW: EVERY wave's tile-tt loads published to LDS]
//   16 ds_read (B 8 + A 8); 32 MFMA in 2 setprio groups.
// (Round-8 bug: VWAIT was AFTER the single barrier -> per-wave vmcnt said
//  nothing about other waves' staging. Two-barrier discipline restored.)
// LDS 144 KiB (3 x 48 KiB). Inputs L3-resident; 2-tile prefetch slack.
// MODE 2 (V): out transposed to vt[b][d][token] + bias via LDS bounce.
// MODE 3 (PV): out f32 / rowsum(lpart).
template <int MODE>
__device__ __forceinline__ void gemm_small_body(
    const ushort* __restrict__ Ag, const ushort* __restrict__ Bg,
    void* __restrict__ C0, const float* __restrict__ x0,
    int N, int Kd, long sA, long sB, long sC)
{
  constexpr int ASZ = 128 * 64;            // 8192 ushorts
  constexpr int BSZ = 256 * 64;            // 16384 ushorts
  __shared__ ushort SH[3 * ASZ + 3 * BSZ]; // 144 KiB

  int nwg = gridDim.x * gridDim.y;
  int id = blockIdx.y * gridDim.x + blockIdx.x;
  int swz = (nwg & 7) ? id : ((id & 7) * (nwg >> 3) + (id >> 3));
  const int m0 = (swz / gridDim.x) * 128;
  const int n0 = (swz % gridDim.x) * 256;
  const int bz = blockIdx.z;
  const char* Ab = (const char*)(Ag + (size_t)bz * sA);
  const char* Bb = (const char*)(Bg + (size_t)bz * sB);
  const int t = threadIdx.x;
  const int lane = t & 63;
  const int w = t >> 6;
  const int wm = w >> 2, wn = w & 3;       // 2M x 4N, wave = 64 x 64
  const size_t pA = (size_t)Kd * 2;
  const size_t pB = (size_t)Kd * 2;
  const int nt = Kd >> 6;

  auto stageH = [&](ushort* ldsb, const char* gb, size_t pitch) {
#pragma unroll
    for (int j = 0; j < 2; ++j) {
      int g = j * 512 + t;
      int r = g >> 3;
      int cb = ((g & 7) << 4) ^ ((r & 7) << 4);
      gload_lds16(gb + (size_t)r * pitch + cb,
                  (char*)ldsb + (size_t)((j * 512 + (t & ~63)) << 4));
    }
  };
  auto ldfrag = [&](const ushort* base, int row, int ks) -> bf16x8 {
    int L = row * 128 + ks * 64 + ((lane >> 4) << 4);
    return *(const bf16x8*)((const char*)base + (L ^ ((row & 7) << 4)));
  };
  auto stageT = [&](int tile) {           // stage full tile -> buf tile%3
    ushort* Abuf = SH + (tile % 3) * ASZ;
    ushort* Bbuf = SH + 3 * ASZ + (tile % 3) * BSZ;
    const size_t ko = (size_t)tile * 128;
    stageH(Abuf, Ab + (size_t)m0 * pA + ko, pA);
    stageH(Bbuf, Bb + (size_t)n0 * pB + ko, pB);
    stageH(Bbuf + 128 * 64, Bb + (size_t)(n0 + 128) * pB + ko, pB);
  };

  f32x4 acc[4][4];
#pragma unroll
  for (int i = 0; i < 4; ++i)
#pragma unroll
    for (int j = 0; j < 4; ++j) acc[i][j] = 0.f;

  bf16x8 a[2][2];
  bf16x8 b[4][2];

  // ---- prologue: stage tiles 0 and 1 ----
  stageT(0);
  stageT(1);

  for (int tt = 0; tt < nt; ++tt) {
    const ushort* Ac = SH + (tt % 3) * ASZ;
    const ushort* Bc = SH + 3 * ASZ + (tt % 3) * BSZ;
    BAR();                                 // WAR: reads of buf (tt+2)%3 done
    if (tt + 2 < nt) { stageT(tt + 2); VWAIT(12); }
    else if (tt + 1 < nt) VWAIT(6);
    else VWAIT(0);
    BAR();                                 // RAW: tile tt published by ALL waves
#pragma unroll
    for (int nf = 0; nf < 4; ++nf) {
      int r = wn * 64 + nf * 16 + (lane & 15);
      b[nf][0] = ldfrag(Bc, r, 0);
      b[nf][1] = ldfrag(Bc, r, 1);
    }
#pragma unroll
    for (int g = 0; g < 2; ++g) {
#pragma unroll
      for (int i = 0; i < 2; ++i) {
        int r = wm * 64 + (g * 2 + i) * 16 + (lane & 15);
        a[i][0] = ldfrag(Ac, r, 0);
        a[i][1] = ldfrag(Ac, r, 1);
      }
      __builtin_amdgcn_s_setprio(1);
#pragma unroll
      for (int i = 0; i < 2; ++i)
#pragma unroll
        for (int nf = 0; nf < 4; ++nf) {
          acc[g * 2 + i][nf] = MFMA16(a[i][0], b[nf][0], acc[g * 2 + i][nf]);
          acc[g * 2 + i][nf] = MFMA16(a[i][1], b[nf][1], acc[g * 2 + i][nf]);
        }
      __builtin_amdgcn_s_setprio(0);
    }
  }

  if constexpr (MODE == 2) {
    // V: block = 128 tokens x 256 d; write vt[b][d][token] via LDS bounce.
    __syncthreads();
    const int b_ = m0 >> 11;
    const int tok0 = m0 & 2047;
    ushort* vtb = (ushort*)C0 + (size_t)b_ * DIM * SEQ;
    ushort* T = SH;                        // [256 d][132 tok]
    {
#pragma unroll
      for (int nf = 0; nf < 4; ++nf) {
        int d_loc = wn * 64 + nf * 16 + (lane & 15);
        float bvv = x0[n0 + d_loc];
#pragma unroll
        for (int mf = 0; mf < 4; ++mf) {
          int tok = wm * 64 + mf * 16 + (lane >> 4) * 4;
          ushort4 pk;
          pk.x = f2b(acc[mf][nf][0] + bvv);
          pk.y = f2b(acc[mf][nf][1] + bvv);
          pk.z = f2b(acc[mf][nf][2] + bvv);
          pk.w = f2b(acc[mf][nf][3] + bvv);
          *(ushort4*)&T[d_loc * 132 + tok] = pk;
        }
      }
    }
    __syncthreads();
    {
      int rr = t >> 1, ch = t & 1;         // 256 d-rows x 2 chunks of 64 tok
      ushort* dst = vtb + (size_t)(n0 + rr) * SEQ + tok0 + ch * 64;
#pragma unroll
      for (int i = 0; i < 8; ++i)
        *(bf16x8*)(dst + i * 8) = *(const bf16x8*)&T[rr * 132 + ch * 64 + i * 8];
    }
  } else {
    // PV: O = acc / rowsum(lpart), f32 out
    const float* lp = x0 + (size_t)bz * SEQ * 8;
    float* Cf = (float*)C0 + (size_t)bz * sC;
#pragma unroll
    for (int mf = 0; mf < 4; ++mf) {
      int row0 = m0 + wm * 64 + mf * 16 + (lane >> 4) * 4;
      float inv[4];
#pragma unroll
      for (int r = 0; r < 4; ++r) {
        const f32x4* q = (const f32x4*)(lp + (size_t)(row0 + r) * 8);
        f32x4 u = q[0] + q[1];
        inv[r] = 1.f / (u[0] + u[1] + u[2] + u[3]);
      }
#pragma unroll
      for (int nf = 0; nf < 4; ++nf) {
        int gn = n0 + wn * 64 + nf * 16 + (lane & 15);
#pragma unroll
        for (int r = 0; r < 4; ++r)
          Cf[(size_t)(row0 + r) * N + gn] = acc[mf][nf][r] * inv[r];
      }
    }
  }
}

__global__ __launch_bounds__(512) void gemm_v(
    const ushort* __restrict__ Ag, const ushort* __restrict__ Bg,
    void* __restrict__ C0, const float* __restrict__ bv) {
  gemm_small_body<2>(Ag, Bg, C0, bv, DIM, DIM, 0, 0, 0);
}
__global__ __launch_bounds__(512) void gemm_pv(
    const ushort* __restrict__ Ag, const ushort* __restrict__ Bg,
    void* __restrict__ C0, const float* __restrict__ lpart) {
  gemm_small_body<3>(Ag, Bg, C0, lpart, DIM, SEQ,
                     (long)SEQ * SEQ, (long)DIM * SEQ, (long)SEQ * DIM);
}

// ---------------- launcher ----------------
extern "C" void kernel_launch(void* const* d_in, const int* in_sizes, int n_in,
                              void* d_out, int out_size, void* d_ws, size_t ws_size,
                              hipStream_t stream) {
  const float* x  = (const float*)d_in[0];
  const float* Wq = (const float*)d_in[1];
  const float* bq = (const float*)d_in[2];
  const float* Wk = (const float*)d_in[3];
  const float* bk = (const float*)d_in[4];
  const float* Wv = (const float*)d_in[5];
  const float* bv = (const float*)d_in[6];
  float* out = (float*)d_out;

  char* ws = (char*)d_ws;
  // ws layout (bytes), total 90.2 MB:
  //   [0, 32M)      SP  [4][2048][2048] bf16 (xb at [16M,32M) dead by then)
  //   [32M, 38.3M)  wb  (dead after gemm_v) / lpart overlay
  //   [38.3M, ...)  qb | kb | vt  (16M each)
  ushort* xb = (ushort*)(ws + 16777216);
  ushort* wb = (ushort*)(ws + 33554432);
  ushort* qb = (ushort*)(ws + 39845888);
  ushort* kb = (ushort*)(ws + 56623104);
  ushort* vt = (ushort*)(ws + 73400320);
  ushort* SP = (ushort*)(ws);
  float* lpart = (float*)(ws + 33554432);  // [4][2048][8] f32, overlays dead wb

  cvt_all<<<11264, 256, 0, stream>>>(x, Wq, Wk, Wv, xb, wb);
  // Q,K: [8192 x 2048] = X . [Wq;Wk]^T + bias.  256 blocks.
  gemm_qk<<<dim3(8, 32, 1), 512, 0, stream>>>(xb, wb, qb, kb, bq, bk);
  // V: [8192 x 1024] = X . Wv^T + bias, transposed to vt.  256 blocks (4x64).
  gemm_v<<<dim3(4, 64, 1), 512, 0, stream>>>(xb, wb + 2097152, vt, bv);
  // P = exp(Q K^T / 32) -> SP (+ row partial sums -> lpart).  256 blocks.
  gemm_s<<<dim3(8, 8, 4), 512, 0, stream>>>(qb, kb, SP, lpart);
  // O = (P V) / rowsum.  256 blocks (4x16x4).
  gemm_pv<<<dim3(4, 16, 4), 512, 0, stream>>>(SP, vt, out, lpart);
}

// Round 11
// 158.894 us; speedup vs baseline: 1.5351x; 1.0132x over previous
//
#include <hip/hip_runtime.h>
#include <hip/hip_bf16.h>

typedef __attribute__((ext_vector_type(4))) float f32x4;
typedef __attribute__((ext_vector_type(8))) short bf16x8;

#define MFMA16(a, b, c) __builtin_amdgcn_mfma_f32_16x16x32_bf16(a, b, c, 0, 0, 0)

constexpr int BATCH = 4;
constexpr int SEQ   = 2048;
constexpr int DIM   = 1024;

__device__ __forceinline__ ushort f2b(float f) {
  __hip_bfloat16 h = __float2bfloat16(f);
  union { __hip_bfloat16 h; ushort u; } cv; cv.h = h; return cv.u;
}

// ---------------- fused fp32 -> bf16 convert ----------------
__global__ __launch_bounds__(256) void cvt_all(
    const float* __restrict__ x, const float* __restrict__ wq,
    const float* __restrict__ wk, const float* __restrict__ wv,
    ushort* __restrict__ xb, ushort* __restrict__ wb) {
  int i = blockIdx.x * 256 + threadIdx.x;
  const float* src; ushort* dst; int off;
  if (i < 2097152) { src = x; dst = xb; off = i; }
  else {
    int j = i - 2097152;
    int s = j >> 18;
    off = j & 262143;
    src = (s == 0) ? wq : (s == 1) ? wk : wv;
    dst = wb + s * 1048576;
  }
  float4 v = reinterpret_cast<const float4*>(src)[off];
  ushort4 o;
  o.x = f2b(v.x); o.y = f2b(v.y); o.z = f2b(v.z); o.w = f2b(v.w);
  reinterpret_cast<ushort4*>(dst)[off] = o;
}

__device__ __forceinline__ void gload_lds16(const void* g, void* l) {
  __builtin_amdgcn_global_load_lds(
      (const __attribute__((address_space(1))) unsigned int*)g,
      (__attribute__((address_space(3))) unsigned int*)l, 16, 0, 0);
}

#define VWAIT(n) asm volatile("s_waitcnt vmcnt(" #n ")" ::: "memory")
#define BAR() __builtin_amdgcn_s_barrier()

// ============ 256x256 8-wave 2-region GEMM, 1Mx8N wave mapping ============
// MODE 0 (QK): unswapped; C routed by seg = n0>>10 to C0/C1 + bias, bf16 out.
// MODE 1 (S):  SWAPPED mfma (D transposed per-fragment): lane holds row
//   gm = m0+mf*16+(lane&15) FIXED, 4 consecutive cols per reg -> ushort4
//   stores + cheap per-row sums.  P = exp(scale*acc), lpart[b][row][8].
template <int MODE>
__device__ __forceinline__ void gemm256_body(
    const ushort* __restrict__ Ag, const ushort* __restrict__ Bg,
    void* __restrict__ C0, void* __restrict__ C1,
    const float* __restrict__ b0, const float* __restrict__ b1,
    float* __restrict__ lpart,
    int N, int Kd, float scale, long sA, long sB, long sC)
{
  constexpr int ASZ = 256 * 64;
  constexpr int BSZ = 256 * 64;
  __shared__ ushort SH[2 * ASZ + 2 * BSZ];

  int nwg = gridDim.x * gridDim.y;
  int id = blockIdx.y * gridDim.x + blockIdx.x;
  int swz = (nwg & 7) ? id : ((id & 7) * (nwg >> 3) + (id >> 3));
  const int m0 = (swz / gridDim.x) * 256;
  const int n0 = (swz % gridDim.x) * 256;
  const int bz = blockIdx.z;
  const char* Ab = (const char*)(Ag + (size_t)bz * sA);
  const char* Bb = (const char*)(Bg + (size_t)bz * sB);
  const int t = threadIdx.x;
  const int lane = t & 63;
  const int w = t >> 6;
  const size_t pA = (size_t)Kd * 2;
  const size_t pB = (size_t)Kd * 2;
  const int nt = Kd >> 6;

  auto stageH = [&](ushort* ldsb, const char* gb, size_t pitch) {
#pragma unroll
    for (int j = 0; j < 2; ++j) {
      int g = j * 512 + t;
      int r = g >> 3;
      int cb = ((g & 7) << 4) ^ ((r & 7) << 4);
      gload_lds16(gb + (size_t)r * pitch + cb,
                  (char*)ldsb + (size_t)((j * 512 + (t & ~63)) << 4));
    }
  };
  auto ldfrag = [&](const ushort* base, int row, int ks) -> bf16x8 {
    int L = row * 128 + ks * 64 + ((lane >> 4) << 4);
    return *(const bf16x8*)((const char*)base + (L ^ ((row & 7) << 4)));
  };

  f32x4 acc[16][2];
#pragma unroll
  for (int i = 0; i < 16; ++i) { acc[i][0] = 0.f; acc[i][1] = 0.f; }

  bf16x8 a[4][2];
  bf16x8 b[2][2];

  // ---- prologue ----
  stageH(SH + 2 * ASZ, Bb + (size_t)n0 * pB, pB);
  stageH(SH + 2 * ASZ + 128 * 64, Bb + (size_t)(n0 + 128) * pB, pB);
  stageH(SH, Ab + (size_t)m0 * pA, pA);
  stageH(SH + 128 * 64, Ab + (size_t)(m0 + 128) * pA, pA);
  VWAIT(0);
  BAR();

  for (int tt = 0; tt < nt; ++tt) {
    const int buf = tt & 1;
    const ushort* Ac = SH + buf * ASZ;
    const ushort* Bc = SH + 2 * ASZ + buf * BSZ;
    ushort* An = SH + (buf ^ 1) * ASZ;
    ushort* Bn = SH + 2 * ASZ + (buf ^ 1) * BSZ;
    const size_t ko1 = (size_t)(tt + 1) * 128;

    // ======== region A: needs B(t) + A-half0(t) ========
    if (tt + 1 < nt) {
      stageH(Bn, Bb + (size_t)n0 * pB + ko1, pB);
      stageH(Bn + 128 * 64, Bb + (size_t)(n0 + 128) * pB + ko1, pB);
      stageH(An, Ab + (size_t)m0 * pA + ko1, pA);
      VWAIT(8);
    } else {
      VWAIT(2);
    }
    BAR();
#pragma unroll
    for (int nf = 0; nf < 2; ++nf) {
      int r = w * 32 + nf * 16 + (lane & 15);
      b[nf][0] = ldfrag(Bc, r, 0);
      b[nf][1] = ldfrag(Bc, r, 1);
    }
#pragma unroll
    for (int g = 0; g < 2; ++g) {
#pragma unroll
      for (int mi = 0; mi < 4; ++mi) {
        int r = (g * 4 + mi) * 16 + (lane & 15);
        a[mi][0] = ldfrag(Ac, r, 0);
        a[mi][1] = ldfrag(Ac, r, 1);
      }
      __builtin_amdgcn_s_setprio(1);
#pragma unroll
      for (int mi = 0; mi < 4; ++mi)
#pragma unroll
        for (int nf = 0; nf < 2; ++nf) {
          if constexpr (MODE == 1) {
            acc[g * 4 + mi][nf] = MFMA16(b[nf][0], a[mi][0], acc[g * 4 + mi][nf]);
            acc[g * 4 + mi][nf] = MFMA16(b[nf][1], a[mi][1], acc[g * 4 + mi][nf]);
          } else {
            acc[g * 4 + mi][nf] = MFMA16(a[mi][0], b[nf][0], acc[g * 4 + mi][nf]);
            acc[g * 4 + mi][nf] = MFMA16(a[mi][1], b[nf][1], acc[g * 4 + mi][nf]);
          }
        }
      __builtin_amdgcn_s_setprio(0);
    }

    // ======== region B: needs A-half1(t) ========
    if (tt + 1 < nt) {
      stageH(An + 128 * 64, Ab + (size_t)(m0 + 128) * pA + ko1, pA);
      VWAIT(8);
    } else {
      VWAIT(0);
    }
    BAR();
#pragma unroll
    for (int g = 2; g < 4; ++g) {
#pragma unroll
      for (int mi = 0; mi < 4; ++mi) {
        int r = (g * 4 + mi) * 16 + (lane & 15);
        a[mi][0] = ldfrag(Ac, r, 0);
        a[mi][1] = ldfrag(Ac, r, 1);
      }
      __builtin_amdgcn_s_setprio(1);
#pragma unroll
      for (int mi = 0; mi < 4; ++mi)
#pragma unroll
        for (int nf = 0; nf < 2; ++nf) {
          if constexpr (MODE == 1) {
            acc[g * 4 + mi][nf] = MFMA16(b[nf][0], a[mi][0], acc[g * 4 + mi][nf]);
            acc[g * 4 + mi][nf] = MFMA16(b[nf][1], a[mi][1], acc[g * 4 + mi][nf]);
          } else {
            acc[g * 4 + mi][nf] = MFMA16(a[mi][0], b[nf][0], acc[g * 4 + mi][nf]);
            acc[g * 4 + mi][nf] = MFMA16(a[mi][1], b[nf][1], acc[g * 4 + mi][nf]);
          }
        }
      __builtin_amdgcn_s_setprio(0);
    }
  }

  if constexpr (MODE == 0) {
    const int seg = n0 >> 10;
    const int n0l = n0 & 1023;
    const float* biasp = seg == 0 ? b0 : b1;
    ushort* Ch = (ushort*)(seg == 0 ? C0 : C1);
#pragma unroll
    for (int mf = 0; mf < 16; ++mf)
#pragma unroll
      for (int nf = 0; nf < 2; ++nf) {
        int gn = n0l + w * 32 + nf * 16 + (lane & 15);
        float bb = biasp[gn];
#pragma unroll
        for (int r = 0; r < 4; ++r) {
          int gm = m0 + mf * 16 + (lane >> 4) * 4 + r;
          Ch[(size_t)gm * N + gn] = f2b(acc[mf][nf][r] * scale + bb);
        }
      }
  } else {
    // S (swapped): lane row gm fixed per mf; 4 consecutive gn per reg.
    ushort* Ch = (ushort*)C0 + (size_t)bz * sC;
    float rs[16];
#pragma unroll
    for (int mf = 0; mf < 16; ++mf) rs[mf] = 0.f;
#pragma unroll
    for (int mf = 0; mf < 16; ++mf) {
      int gm = m0 + mf * 16 + (lane & 15);
#pragma unroll
      for (int nf = 0; nf < 2; ++nf) {
        int gn0 = n0 + w * 32 + nf * 16 + (lane >> 4) * 4;
        float e0 = __expf(acc[mf][nf][0] * scale);
        float e1 = __expf(acc[mf][nf][1] * scale);
        float e2 = __expf(acc[mf][nf][2] * scale);
        float e3 = __expf(acc[mf][nf][3] * scale);
        rs[mf] += (e0 + e1) + (e2 + e3);
        ushort4 pk;
        pk.x = f2b(e0); pk.y = f2b(e1); pk.z = f2b(e2); pk.w = f2b(e3);
        *(ushort4*)&Ch[(size_t)gm * N + gn0] = pk;
      }
      rs[mf] += __shfl_xor(rs[mf], 16);
      rs[mf] += __shfl_xor(rs[mf], 32);
    }
    __syncthreads();
    float* Lred = (float*)SH;              // [8 waves][256 rows]
#pragma unroll
    for (int mf = 0; mf < 16; ++mf)
      if (lane < 16) Lred[w * 256 + mf * 16 + lane] = rs[mf];
    __syncthreads();
    if (t < 256) {
      float s = 0.f;
#pragma unroll
      for (int ww = 0; ww < 8; ++ww) s += Lred[ww * 256 + t];
      lpart[((size_t)bz * SEQ + m0 + t) * 8 + (n0 >> 8)] = s;
    }
  }
}

__global__ __launch_bounds__(512) void gemm_qk(
    const ushort* __restrict__ Ag, const ushort* __restrict__ Bg,
    void* __restrict__ C0, void* __restrict__ C1,
    const float* __restrict__ b0, const float* __restrict__ b1) {
  gemm256_body<0>(Ag, Bg, C0, C1, b0, b1, nullptr, DIM, DIM, 1.0f, 0, 0, 0);
}
__global__ __launch_bounds__(512) void gemm_s(
    const ushort* __restrict__ Ag, const ushort* __restrict__ Bg,
    void* __restrict__ C0, float* __restrict__ lpart) {
  gemm256_body<1>(Ag, Bg, C0, nullptr, nullptr, nullptr, lpart,
                  SEQ, DIM, 0.03125f, (long)SEQ * DIM, (long)SEQ * DIM,
                  (long)SEQ * SEQ);
}

// ====== 128x256 8-wave TRIPLE-BUFFERED GEMM (2Mx4N, wave 64x64) ======
// Two-barrier discipline (round-9): BAR1 (WAR) / stage t+2 / VWAIT(12) /
// BAR2 (RAW) / reads + MFMA.  LDS 144 KiB (3-deep), 2-tile prefetch slack.
// MODE 2 (V): unswapped; out transposed to vt[b][d][token] via LDS bounce.
// MODE 3 (PV): SWAPPED mfma; f32x4 coalesced stores, 4 inv/thread.
template <int MODE>
__device__ __forceinline__ void gemm_small_body(
    const ushort* __restrict__ Ag, const ushort* __restrict__ Bg,
    void* __restrict__ C0, const float* __restrict__ x0,
    int N, int Kd, long sA, long sB, long sC)
{
  constexpr int ASZ = 128 * 64;            // 8192 ushorts
  constexpr int BSZ = 256 * 64;            // 16384 ushorts
  __shared__ ushort SH[3 * ASZ + 3 * BSZ]; // 144 KiB

  int nwg = gridDim.x * gridDim.y;
  int id = blockIdx.y * gridDim.x + blockIdx.x;
  int swz = (nwg & 7) ? id : ((id & 7) * (nwg >> 3) + (id >> 3));
  const int m0 = (swz / gridDim.x) * 128;
  const int n0 = (swz % gridDim.x) * 256;
  const int bz = blockIdx.z;
  const char* Ab = (const char*)(Ag + (size_t)bz * sA);
  const char* Bb = (const char*)(Bg + (size_t)bz * sB);
  const int t = threadIdx.x;
  const int lane = t & 63;
  const int w = t >> 6;
  const int wm = w >> 2, wn = w & 3;       // 2M x 4N, wave = 64 x 64
  const size_t pA = (size_t)Kd * 2;
  const size_t pB = (size_t)Kd * 2;
  const int nt = Kd >> 6;

  auto stageH = [&](ushort* ldsb, const char* gb, size_t pitch) {
#pragma unroll
    for (int j = 0; j < 2; ++j) {
      int g = j * 512 + t;
      int r = g >> 3;
      int cb = ((g & 7) << 4) ^ ((r & 7) << 4);
      gload_lds16(gb + (size_t)r * pitch + cb,
                  (char*)ldsb + (size_t)((j * 512 + (t & ~63)) << 4));
    }
  };
  auto ldfrag = [&](const ushort* base, int row, int ks) -> bf16x8 {
    int L = row * 128 + ks * 64 + ((lane >> 4) << 4);
    return *(const bf16x8*)((const char*)base + (L ^ ((row & 7) << 4)));
  };
  auto stageT = [&](int tile) {
    ushort* Abuf = SH + (tile % 3) * ASZ;
    ushort* Bbuf = SH + 3 * ASZ + (tile % 3) * BSZ;
    const size_t ko = (size_t)tile * 128;
    stageH(Abuf, Ab + (size_t)m0 * pA + ko, pA);
    stageH(Bbuf, Bb + (size_t)n0 * pB + ko, pB);
    stageH(Bbuf + 128 * 64, Bb + (size_t)(n0 + 128) * pB + ko, pB);
  };

  f32x4 acc[4][4];
#pragma unroll
  for (int i = 0; i < 4; ++i)
#pragma unroll
    for (int j = 0; j < 4; ++j) acc[i][j] = 0.f;

  bf16x8 a[2][2];
  bf16x8 b[4][2];

  // ---- prologue: stage tiles 0 and 1 ----
  stageT(0);
  stageT(1);

  for (int tt = 0; tt < nt; ++tt) {
    const ushort* Ac = SH + (tt % 3) * ASZ;
    const ushort* Bc = SH + 3 * ASZ + (tt % 3) * BSZ;
    BAR();                                 // WAR: reads of buf (tt+2)%3 done
    if (tt + 2 < nt) { stageT(tt + 2); VWAIT(12); }
    else if (tt + 1 < nt) VWAIT(6);
    else VWAIT(0);
    BAR();                                 // RAW: tile tt published by ALL waves
#pragma unroll
    for (int nf = 0; nf < 4; ++nf) {
      int r = wn * 64 + nf * 16 + (lane & 15);
      b[nf][0] = ldfrag(Bc, r, 0);
      b[nf][1] = ldfrag(Bc, r, 1);
    }
#pragma unroll
    for (int g = 0; g < 2; ++g) {
#pragma unroll
      for (int i = 0; i < 2; ++i) {
        int r = wm * 64 + (g * 2 + i) * 16 + (lane & 15);
        a[i][0] = ldfrag(Ac, r, 0);
        a[i][1] = ldfrag(Ac, r, 1);
      }
      __builtin_amdgcn_s_setprio(1);
#pragma unroll
      for (int i = 0; i < 2; ++i)
#pragma unroll
        for (int nf = 0; nf < 4; ++nf) {
          if constexpr (MODE == 3) {
            acc[g * 2 + i][nf] = MFMA16(b[nf][0], a[i][0], acc[g * 2 + i][nf]);
            acc[g * 2 + i][nf] = MFMA16(b[nf][1], a[i][1], acc[g * 2 + i][nf]);
          } else {
            acc[g * 2 + i][nf] = MFMA16(a[i][0], b[nf][0], acc[g * 2 + i][nf]);
            acc[g * 2 + i][nf] = MFMA16(a[i][1], b[nf][1], acc[g * 2 + i][nf]);
          }
        }
      __builtin_amdgcn_s_setprio(0);
    }
  }

  if constexpr (MODE == 2) {
    // V: block = 128 tokens x 256 d; write vt[b][d][token] via LDS bounce.
    __syncthreads();
    const int b_ = m0 >> 11;
    const int tok0 = m0 & 2047;
    ushort* vtb = (ushort*)C0 + (size_t)b_ * DIM * SEQ;
    ushort* T = SH;                        // [256 d][132 tok]
    {
#pragma unroll
      for (int nf = 0; nf < 4; ++nf) {
        int d_loc = wn * 64 + nf * 16 + (lane & 15);
        float bvv = x0[n0 + d_loc];
#pragma unroll
        for (int mf = 0; mf < 4; ++mf) {
          int tok = wm * 64 + mf * 16 + (lane >> 4) * 4;
          ushort4 pk;
          pk.x = f2b(acc[mf][nf][0] + bvv);
          pk.y = f2b(acc[mf][nf][1] + bvv);
          pk.z = f2b(acc[mf][nf][2] + bvv);
          pk.w = f2b(acc[mf][nf][3] + bvv);
          *(ushort4*)&T[d_loc * 132 + tok] = pk;
        }
      }
    }
    __syncthreads();
    {
      int rr = t >> 1, ch = t & 1;         // 256 d-rows x 2 chunks of 64 tok
      ushort* dst = vtb + (size_t)(n0 + rr) * SEQ + tok0 + ch * 64;
#pragma unroll
      for (int i = 0; i < 8; ++i)
        *(bf16x8*)(dst + i * 8) = *(const bf16x8*)&T[rr * 132 + ch * 64 + i * 8];
    }
  } else {
    // PV (swapped): lane row fixed per mf; 4 consecutive gn per reg.
    const float* lp = x0 + (size_t)bz * SEQ * 8;
    float* Cf = (float*)C0 + (size_t)bz * sC;
#pragma unroll
    for (int mf = 0; mf < 4; ++mf) {
      int row = m0 + wm * 64 + mf * 16 + (lane & 15);
      const f32x4* q = (const f32x4*)(lp + (size_t)row * 8);
      f32x4 u = q[0] + q[1];
      float inv = 1.f / ((u[0] + u[1]) + (u[2] + u[3]));
#pragma unroll
      for (int nf = 0; nf < 4; ++nf) {
        int gn0 = n0 + wn * 64 + nf * 16 + (lane >> 4) * 4;
        f32x4 o = acc[mf][nf] * inv;
        *(f32x4*)&Cf[(size_t)row * N + gn0] = o;
      }
    }
  }
}

__global__ __launch_bounds__(512) void gemm_v(
    const ushort* __restrict__ Ag, const ushort* __restrict__ Bg,
    void* __restrict__ C0, const float* __restrict__ bv) {
  gemm_small_body<2>(Ag, Bg, C0, bv, DIM, DIM, 0, 0, 0);
}
__global__ __launch_bounds__(512) void gemm_pv(
    const ushort* __restrict__ Ag, const ushort* __restrict__ Bg,
    void* __restrict__ C0, const float* __restrict__ lpart) {
  gemm_small_body<3>(Ag, Bg, C0, lpart, DIM, SEQ,
                     (long)SEQ * SEQ, (long)DIM * SEQ, (long)SEQ * DIM);
}

// ---------------- launcher ----------------
extern "C" void kernel_launch(void* const* d_in, const int* in_sizes, int n_in,
                              void* d_out, int out_size, void* d_ws, size_t ws_size,
                              hipStream_t stream) {
  const float* x  = (const float*)d_in[0];
  const float* Wq = (const float*)d_in[1];
  const float* bq = (const float*)d_in[2];
  const float* Wk = (const float*)d_in[3];
  const float* bk = (const float*)d_in[4];
  const float* Wv = (const float*)d_in[5];
  const float* bv = (const float*)d_in[6];
  float* out = (float*)d_out;

  char* ws = (char*)d_ws;
  // ws layout (bytes), total 90.2 MB:
  //   [0, 32M)      SP  [4][2048][2048] bf16 (xb at [16M,32M) dead by then)
  //   [32M, 38.3M)  wb  (dead after gemm_v) / lpart overlay
  //   [38.3M, ...)  qb | kb | vt  (16M each)
  ushort* xb = (ushort*)(ws + 16777216);
  ushort* wb = (ushort*)(ws + 33554432);
  ushort* qb = (ushort*)(ws + 39845888);
  ushort* kb = (ushort*)(ws + 56623104);
  ushort* vt = (ushort*)(ws + 73400320);
  ushort* SP = (ushort*)(ws);
  float* lpart = (float*)(ws + 33554432);  // [4][2048][8] f32, overlays dead wb

  cvt_all<<<11264, 256, 0, stream>>>(x, Wq, Wk, Wv, xb, wb);
  // Q,K: [8192 x 2048] = X . [Wq;Wk]^T + bias.  256 blocks.
  gemm_qk<<<dim3(8, 32, 1), 512, 0, stream>>>(xb, wb, qb, kb, bq, bk);
  // V: [8192 x 1024] = X . Wv^T + bias, transposed to vt.  256 blocks (4x64).
  gemm_v<<<dim3(4, 64, 1), 512, 0, stream>>>(xb, wb + 2097152, vt, bv);
  // P = exp(Q K^T / 32) -> SP (+ row partial sums -> lpart).  256 blocks.
  gemm_s<<<dim3(8, 8, 4), 512, 0, stream>>>(qb, kb, SP, lpart);
  // O = (P V) / rowsum.  256 blocks (4x16x4).
  gemm_pv<<<dim3(4, 16, 4), 512, 0, stream>>>(SP, vt, out, lpart);
}

// Round 12
// 158.439 us; speedup vs baseline: 1.5395x; 1.0029x over previous
//
#include <hip/hip_runtime.h>
#include <hip/hip_bf16.h>

typedef __attribute__((ext_vector_type(4))) float f32x4;
typedef __attribute__((ext_vector_type(8))) short bf16x8;

#define MFMA16(a, b, c) __builtin_amdgcn_mfma_f32_16x16x32_bf16(a, b, c, 0, 0, 0)

constexpr int BATCH = 4;
constexpr int SEQ   = 2048;
constexpr int DIM   = 1024;

__device__ __forceinline__ ushort f2b(float f) {
  __hip_bfloat16 h = __float2bfloat16(f);
  union { __hip_bfloat16 h; ushort u; } cv; cv.h = h; return cv.u;
}

// ---------------- fused fp32 -> bf16 convert ----------------
__global__ __launch_bounds__(256) void cvt_all(
    const float* __restrict__ x, const float* __restrict__ wq,
    const float* __restrict__ wk, const float* __restrict__ wv,
    ushort* __restrict__ xb, ushort* __restrict__ wb) {
  int i = blockIdx.x * 256 + threadIdx.x;
  const float* src; ushort* dst; int off;
  if (i < 2097152) { src = x; dst = xb; off = i; }
  else {
    int j = i - 2097152;
    int s = j >> 18;
    off = j & 262143;
    src = (s == 0) ? wq : (s == 1) ? wk : wv;
    dst = wb + s * 1048576;
  }
  float4 v = reinterpret_cast<const float4*>(src)[off];
  ushort4 o;
  o.x = f2b(v.x); o.y = f2b(v.y); o.z = f2b(v.z); o.w = f2b(v.w);
  reinterpret_cast<ushort4*>(dst)[off] = o;
}

__device__ __forceinline__ void gload_lds16(const void* g, void* l) {
  __builtin_amdgcn_global_load_lds(
      (const __attribute__((address_space(1))) unsigned int*)g,
      (__attribute__((address_space(3))) unsigned int*)l, 16, 0, 0);
}

#define VWAIT(n) asm volatile("s_waitcnt vmcnt(" #n ")" ::: "memory")
#define BAR() __builtin_amdgcn_s_barrier()

// ====== 256x256 8-wave dbuf GEMM, 2Mx4N wave mapping (wave = 128x64) ======
// Per K-tile(64): BAR1 (WAR) / stage full tile t+1 (8 gload_lds) / VWAIT(8)
// [drains tile t, staged one full iteration ago] / BAR2 (RAW publish) /
// 8 B-reads + 4 groups {4 A-reads, 16 MFMA setprio-wrapped}.
// ds_read: 24/wave/tile (vs 36 at 1Mx8N — wave aspect 128x64 minimizes
// (rows+cols)/rows*cols operand traffic). LDS 128 KiB.
// MODE 0 (QK): unswapped; routed by seg = n0>>10 to C0/C1 + bias, bf16 out.
// MODE 1 (S):  SWAPPED mfma: lane&15 = row (fixed), 4 consecutive cols/reg
//   -> ushort4 stores + cheap row sums.  P = exp(scale*acc), lpart[b][row][8].
template <int MODE>
__device__ __forceinline__ void gemm256_body(
    const ushort* __restrict__ Ag, const ushort* __restrict__ Bg,
    void* __restrict__ C0, void* __restrict__ C1,
    const float* __restrict__ b0, const float* __restrict__ b1,
    float* __restrict__ lpart,
    int N, int Kd, float scale, long sA, long sB, long sC)
{
  constexpr int ASZ = 256 * 64;
  constexpr int BSZ = 256 * 64;
  __shared__ ushort SH[2 * ASZ + 2 * BSZ];

  int nwg = gridDim.x * gridDim.y;
  int id = blockIdx.y * gridDim.x + blockIdx.x;
  int swz = (nwg & 7) ? id : ((id & 7) * (nwg >> 3) + (id >> 3));
  const int m0 = (swz / gridDim.x) * 256;
  const int n0 = (swz % gridDim.x) * 256;
  const int bz = blockIdx.z;
  const char* Ab = (const char*)(Ag + (size_t)bz * sA);
  const char* Bb = (const char*)(Bg + (size_t)bz * sB);
  const int t = threadIdx.x;
  const int lane = t & 63;
  const int w = t >> 6;
  const int wm = w >> 2, wn = w & 3;       // 2M x 4N, wave = 128 x 64
  const size_t pA = (size_t)Kd * 2;
  const size_t pB = (size_t)Kd * 2;
  const int nt = Kd >> 6;

  auto stageH = [&](ushort* ldsb, const char* gb, size_t pitch) {
#pragma unroll
    for (int j = 0; j < 2; ++j) {
      int g = j * 512 + t;
      int r = g >> 3;
      int cb = ((g & 7) << 4) ^ ((r & 7) << 4);
      gload_lds16(gb + (size_t)r * pitch + cb,
                  (char*)ldsb + (size_t)((j * 512 + (t & ~63)) << 4));
    }
  };
  auto ldfrag = [&](const ushort* base, int row, int ks) -> bf16x8 {
    int L = row * 128 + ks * 64 + ((lane >> 4) << 4);
    return *(const bf16x8*)((const char*)base + (L ^ ((row & 7) << 4)));
  };
  auto stageT = [&](int tile) {            // full tile -> buf tile&1 (8 loads)
    ushort* Abuf = SH + (tile & 1) * ASZ;
    ushort* Bbuf = SH + 2 * ASZ + (tile & 1) * BSZ;
    const size_t ko = (size_t)tile * 128;
    stageH(Abuf, Ab + (size_t)m0 * pA + ko, pA);
    stageH(Abuf + 128 * 64, Ab + (size_t)(m0 + 128) * pA + ko, pA);
    stageH(Bbuf, Bb + (size_t)n0 * pB + ko, pB);
    stageH(Bbuf + 128 * 64, Bb + (size_t)(n0 + 128) * pB + ko, pB);
  };

  f32x4 acc[8][4];
#pragma unroll
  for (int i = 0; i < 8; ++i)
#pragma unroll
    for (int j = 0; j < 4; ++j) acc[i][j] = 0.f;

  bf16x8 a[2][2];
  bf16x8 b[4][2];

  // ---- prologue: stage tile 0 only ----
  stageT(0);

  for (int tt = 0; tt < nt; ++tt) {
    const int buf = tt & 1;
    const ushort* Ac = SH + buf * ASZ;
    const ushort* Bc = SH + 2 * ASZ + buf * BSZ;
    BAR();                                 // WAR: reads of buf^1 (tile tt-1) done
    if (tt + 1 < nt) { stageT(tt + 1); VWAIT(8); }
    else VWAIT(0);
    BAR();                                 // RAW: tile tt published by ALL waves
#pragma unroll
    for (int nf = 0; nf < 4; ++nf) {
      int r = wn * 64 + nf * 16 + (lane & 15);
      b[nf][0] = ldfrag(Bc, r, 0);
      b[nf][1] = ldfrag(Bc, r, 1);
    }
#pragma unroll
    for (int g = 0; g < 4; ++g) {
#pragma unroll
      for (int i = 0; i < 2; ++i) {
        int r = wm * 128 + (g * 2 + i) * 16 + (lane & 15);
        a[i][0] = ldfrag(Ac, r, 0);
        a[i][1] = ldfrag(Ac, r, 1);
      }
      __builtin_amdgcn_s_setprio(1);
#pragma unroll
      for (int i = 0; i < 2; ++i)
#pragma unroll
        for (int nf = 0; nf < 4; ++nf) {
          if constexpr (MODE == 1) {
            acc[g * 2 + i][nf] = MFMA16(b[nf][0], a[i][0], acc[g * 2 + i][nf]);
            acc[g * 2 + i][nf] = MFMA16(b[nf][1], a[i][1], acc[g * 2 + i][nf]);
          } else {
            acc[g * 2 + i][nf] = MFMA16(a[i][0], b[nf][0], acc[g * 2 + i][nf]);
            acc[g * 2 + i][nf] = MFMA16(a[i][1], b[nf][1], acc[g * 2 + i][nf]);
          }
        }
      __builtin_amdgcn_s_setprio(0);
    }
  }

  if constexpr (MODE == 0) {
    const int seg = n0 >> 10;
    const int n0l = n0 & 1023;
    const float* biasp = seg == 0 ? b0 : b1;
    ushort* Ch = (ushort*)(seg == 0 ? C0 : C1);
#pragma unroll
    for (int mf = 0; mf < 8; ++mf)
#pragma unroll
      for (int nf = 0; nf < 4; ++nf) {
        int gn = n0l + wn * 64 + nf * 16 + (lane & 15);
        float bb = biasp[gn];
#pragma unroll
        for (int r = 0; r < 4; ++r) {
          int gm = m0 + wm * 128 + mf * 16 + (lane >> 4) * 4 + r;
          Ch[(size_t)gm * N + gn] = f2b(acc[mf][nf][r] * scale + bb);
        }
      }
  } else {
    // S (swapped): lane row gm fixed per mf; 4 consecutive gn per reg.
    ushort* Ch = (ushort*)C0 + (size_t)bz * sC;
    float rs[8];
#pragma unroll
    for (int mf = 0; mf < 8; ++mf) rs[mf] = 0.f;
#pragma unroll
    for (int mf = 0; mf < 8; ++mf) {
      int gm = m0 + wm * 128 + mf * 16 + (lane & 15);
#pragma unroll
      for (int nf = 0; nf < 4; ++nf) {
        int gn0 = n0 + wn * 64 + nf * 16 + (lane >> 4) * 4;
        float e0 = __expf(acc[mf][nf][0] * scale);
        float e1 = __expf(acc[mf][nf][1] * scale);
        float e2 = __expf(acc[mf][nf][2] * scale);
        float e3 = __expf(acc[mf][nf][3] * scale);
        rs[mf] += (e0 + e1) + (e2 + e3);
        ushort4 pk;
        pk.x = f2b(e0); pk.y = f2b(e1); pk.z = f2b(e2); pk.w = f2b(e3);
        *(ushort4*)&Ch[(size_t)gm * N + gn0] = pk;
      }
      rs[mf] += __shfl_xor(rs[mf], 16);
      rs[mf] += __shfl_xor(rs[mf], 32);
    }
    __syncthreads();
    float* Lred = (float*)SH;              // [4 wn][256 rows]
#pragma unroll
    for (int mf = 0; mf < 8; ++mf)
      if (lane < 16) Lred[wn * 256 + wm * 128 + mf * 16 + lane] = rs[mf];
    __syncthreads();
    if (t < 256) {
      float s = Lred[t] + Lred[256 + t] + Lred[512 + t] + Lred[768 + t];
      lpart[((size_t)bz * SEQ + m0 + t) * 8 + (n0 >> 8)] = s;
    }
  }
}

__global__ __launch_bounds__(512) void gemm_qk(
    const ushort* __restrict__ Ag, const ushort* __restrict__ Bg,
    void* __restrict__ C0, void* __restrict__ C1,
    const float* __restrict__ b0, const float* __restrict__ b1) {
  gemm256_body<0>(Ag, Bg, C0, C1, b0, b1, nullptr, DIM, DIM, 1.0f, 0, 0, 0);
}
__global__ __launch_bounds__(512) void gemm_s(
    const ushort* __restrict__ Ag, const ushort* __restrict__ Bg,
    void* __restrict__ C0, float* __restrict__ lpart) {
  gemm256_body<1>(Ag, Bg, C0, nullptr, nullptr, nullptr, lpart,
                  SEQ, DIM, 0.03125f, (long)SEQ * DIM, (long)SEQ * DIM,
                  (long)SEQ * SEQ);
}

// ====== 128x256 8-wave TRIPLE-BUFFERED GEMM (2Mx4N, wave 64x64) ======
// Two-barrier discipline: BAR1 (WAR) / stage t+2 / VWAIT(12) / BAR2 (RAW) /
// reads + MFMA.  LDS 144 KiB (3-deep), 2-tile prefetch slack.
// MODE 2 (V): unswapped; out transposed to vt[b][d][token] via LDS bounce.
// MODE 3 (PV): SWAPPED mfma; f32x4 coalesced stores, 1 inv/row.
template <int MODE>
__device__ __forceinline__ void gemm_small_body(
    const ushort* __restrict__ Ag, const ushort* __restrict__ Bg,
    void* __restrict__ C0, const float* __restrict__ x0,
    int N, int Kd, long sA, long sB, long sC)
{
  constexpr int ASZ = 128 * 64;            // 8192 ushorts
  constexpr int BSZ = 256 * 64;            // 16384 ushorts
  __shared__ ushort SH[3 * ASZ + 3 * BSZ]; // 144 KiB

  int nwg = gridDim.x * gridDim.y;
  int id = blockIdx.y * gridDim.x + blockIdx.x;
  int swz = (nwg & 7) ? id : ((id & 7) * (nwg >> 3) + (id >> 3));
  const int m0 = (swz / gridDim.x) * 128;
  const int n0 = (swz % gridDim.x) * 256;
  const int bz = blockIdx.z;
  const char* Ab = (const char*)(Ag + (size_t)bz * sA);
  const char* Bb = (const char*)(Bg + (size_t)bz * sB);
  const int t = threadIdx.x;
  const int lane = t & 63;
  const int w = t >> 6;
  const int wm = w >> 2, wn = w & 3;       // 2M x 4N, wave = 64 x 64
  const size_t pA = (size_t)Kd * 2;
  const size_t pB = (size_t)Kd * 2;
  const int nt = Kd >> 6;

  auto stageH = [&](ushort* ldsb, const char* gb, size_t pitch) {
#pragma unroll
    for (int j = 0; j < 2; ++j) {
      int g = j * 512 + t;
      int r = g >> 3;
      int cb = ((g & 7) << 4) ^ ((r & 7) << 4);
      gload_lds16(gb + (size_t)r * pitch + cb,
                  (char*)ldsb + (size_t)((j * 512 + (t & ~63)) << 4));
    }
  };
  auto ldfrag = [&](const ushort* base, int row, int ks) -> bf16x8 {
    int L = row * 128 + ks * 64 + ((lane >> 4) << 4);
    return *(const bf16x8*)((const char*)base + (L ^ ((row & 7) << 4)));
  };
  auto stageT = [&](int tile) {
    ushort* Abuf = SH + (tile % 3) * ASZ;
    ushort* Bbuf = SH + 3 * ASZ + (tile % 3) * BSZ;
    const size_t ko = (size_t)tile * 128;
    stageH(Abuf, Ab + (size_t)m0 * pA + ko, pA);
    stageH(Bbuf, Bb + (size_t)n0 * pB + ko, pB);
    stageH(Bbuf + 128 * 64, Bb + (size_t)(n0 + 128) * pB + ko, pB);
  };

  f32x4 acc[4][4];
#pragma unroll
  for (int i = 0; i < 4; ++i)
#pragma unroll
    for (int j = 0; j < 4; ++j) acc[i][j] = 0.f;

  bf16x8 a[2][2];
  bf16x8 b[4][2];

  // ---- prologue: stage tiles 0 and 1 ----
  stageT(0);
  stageT(1);

  for (int tt = 0; tt < nt; ++tt) {
    const ushort* Ac = SH + (tt % 3) * ASZ;
    const ushort* Bc = SH + 3 * ASZ + (tt % 3) * BSZ;
    BAR();                                 // WAR: reads of buf (tt+2)%3 done
    if (tt + 2 < nt) { stageT(tt + 2); VWAIT(12); }
    else if (tt + 1 < nt) VWAIT(6);
    else VWAIT(0);
    BAR();                                 // RAW: tile tt published by ALL waves
#pragma unroll
    for (int nf = 0; nf < 4; ++nf) {
      int r = wn * 64 + nf * 16 + (lane & 15);
      b[nf][0] = ldfrag(Bc, r, 0);
      b[nf][1] = ldfrag(Bc, r, 1);
    }
#pragma unroll
    for (int g = 0; g < 2; ++g) {
#pragma unroll
      for (int i = 0; i < 2; ++i) {
        int r = wm * 64 + (g * 2 + i) * 16 + (lane & 15);
        a[i][0] = ldfrag(Ac, r, 0);
        a[i][1] = ldfrag(Ac, r, 1);
      }
      __builtin_amdgcn_s_setprio(1);
#pragma unroll
      for (int i = 0; i < 2; ++i)
#pragma unroll
        for (int nf = 0; nf < 4; ++nf) {
          if constexpr (MODE == 3) {
            acc[g * 2 + i][nf] = MFMA16(b[nf][0], a[i][0], acc[g * 2 + i][nf]);
            acc[g * 2 + i][nf] = MFMA16(b[nf][1], a[i][1], acc[g * 2 + i][nf]);
          } else {
            acc[g * 2 + i][nf] = MFMA16(a[i][0], b[nf][0], acc[g * 2 + i][nf]);
            acc[g * 2 + i][nf] = MFMA16(a[i][1], b[nf][1], acc[g * 2 + i][nf]);
          }
        }
      __builtin_amdgcn_s_setprio(0);
    }
  }

  if constexpr (MODE == 2) {
    // V: block = 128 tokens x 256 d; write vt[b][d][token] via LDS bounce.
    __syncthreads();
    const int b_ = m0 >> 11;
    const int tok0 = m0 & 2047;
    ushort* vtb = (ushort*)C0 + (size_t)b_ * DIM * SEQ;
    ushort* T = SH;                        // [256 d][132 tok]
    {
#pragma unroll
      for (int nf = 0; nf < 4; ++nf) {
        int d_loc = wn * 64 + nf * 16 + (lane & 15);
        float bvv = x0[n0 + d_loc];
#pragma unroll
        for (int mf = 0; mf < 4; ++mf) {
          int tok = wm * 64 + mf * 16 + (lane >> 4) * 4;
          ushort4 pk;
          pk.x = f2b(acc[mf][nf][0] + bvv);
          pk.y = f2b(acc[mf][nf][1] + bvv);
          pk.z = f2b(acc[mf][nf][2] + bvv);
          pk.w = f2b(acc[mf][nf][3] + bvv);
          *(ushort4*)&T[d_loc * 132 + tok] = pk;
        }
      }
    }
    __syncthreads();
    {
      int rr = t >> 1, ch = t & 1;         // 256 d-rows x 2 chunks of 64 tok
      ushort* dst = vtb + (size_t)(n0 + rr) * SEQ + tok0 + ch * 64;
#pragma unroll
      for (int i = 0; i < 8; ++i)
        *(bf16x8*)(dst + i * 8) = *(const bf16x8*)&T[rr * 132 + ch * 64 + i * 8];
    }
  } else {
    // PV (swapped): lane row fixed per mf; 4 consecutive gn per reg.
    const float* lp = x0 + (size_t)bz * SEQ * 8;
    float* Cf = (float*)C0 + (size_t)bz * sC;
#pragma unroll
    for (int mf = 0; mf < 4; ++mf) {
      int row = m0 + wm * 64 + mf * 16 + (lane & 15);
      const f32x4* q = (const f32x4*)(lp + (size_t)row * 8);
      f32x4 u = q[0] + q[1];
      float inv = 1.f / ((u[0] + u[1]) + (u[2] + u[3]));
#pragma unroll
      for (int nf = 0; nf < 4; ++nf) {
        int gn0 = n0 + wn * 64 + nf * 16 + (lane >> 4) * 4;
        f32x4 o = acc[mf][nf] * inv;
        *(f32x4*)&Cf[(size_t)row * N + gn0] = o;
      }
    }
  }
}

__global__ __launch_bounds__(512) void gemm_v(
    const ushort* __restrict__ Ag, const ushort* __restrict__ Bg,
    void* __restrict__ C0, const float* __restrict__ bv) {
  gemm_small_body<2>(Ag, Bg, C0, bv, DIM, DIM, 0, 0, 0);
}
__global__ __launch_bounds__(512) void gemm_pv(
    const ushort* __restrict__ Ag, const ushort* __restrict__ Bg,
    void* __restrict__ C0, const float* __restrict__ lpart) {
  gemm_small_body<3>(Ag, Bg, C0, lpart, DIM, SEQ,
                     (long)SEQ * SEQ, (long)DIM * SEQ, (long)SEQ * DIM);
}

// ---------------- launcher ----------------
extern "C" void kernel_launch(void* const* d_in, const int* in_sizes, int n_in,
                              void* d_out, int out_size, void* d_ws, size_t ws_size,
                              hipStream_t stream) {
  const float* x  = (const float*)d_in[0];
  const float* Wq = (const float*)d_in[1];
  const float* bq = (const float*)d_in[2];
  const float* Wk = (const float*)d_in[3];
  const float* bk = (const float*)d_in[4];
  const float* Wv = (const float*)d_in[5];
  const float* bv = (const float*)d_in[6];
  float* out = (float*)d_out;

  char* ws = (char*)d_ws;
  // ws layout (bytes), total 90.2 MB:
  //   [0, 32M)      SP  [4][2048][2048] bf16 (xb at [16M,32M) dead by then)
  //   [32M, 38.3M)  wb  (dead after gemm_v) / lpart overlay
  //   [38.3M, ...)  qb | kb | vt  (16M each)
  ushort* xb = (ushort*)(ws + 16777216);
  ushort* wb = (ushort*)(ws + 33554432);
  ushort* qb = (ushort*)(ws + 39845888);
  ushort* kb = (ushort*)(ws + 56623104);
  ushort* vt = (ushort*)(ws + 73400320);
  ushort* SP = (ushort*)(ws);
  float* lpart = (float*)(ws + 33554432);  // [4][2048][8] f32, overlays dead wb

  cvt_all<<<11264, 256, 0, stream>>>(x, Wq, Wk, Wv, xb, wb);
  // Q,K: [8192 x 2048] = X . [Wq;Wk]^T + bias.  256 blocks.
  gemm_qk<<<dim3(8, 32, 1), 512, 0, stream>>>(xb, wb, qb, kb, bq, bk);
  // V: [8192 x 1024] = X . Wv^T + bias, transposed to vt.  256 blocks (4x64).
  gemm_v<<<dim3(4, 64, 1), 512, 0, stream>>>(xb, wb + 2097152, vt, bv);
  // P = exp(Q K^T / 32) -> SP (+ row partial sums -> lpart).  256 blocks.
  gemm_s<<<dim3(8, 8, 4), 512, 0, stream>>>(qb, kb, SP, lpart);
  // O = (P V) / rowsum.  256 blocks (4x16x4).
  gemm_pv<<<dim3(4, 16, 4), 512, 0, stream>>>(SP, vt, out, lpart);
}